// Round 1
// baseline (404.068 us; speedup 1.0000x reference)
//
#include <hip/hip_runtime.h>
#include <hip/hip_bf16.h>
#include <math.h>

typedef float  f4 __attribute__((ext_vector_type(4)));
typedef short  s8 __attribute__((ext_vector_type(8)));
typedef short  s4 __attribute__((ext_vector_type(4)));

#define NV 28
#define HID 64
#define NB 32768
#define BN_EPS 1e-5f

// workspace float-index offsets
#define SX_OFF     0      // 28
#define SXX_OFF    28     // 784
#define SUM2_OFF   812    // 1792
#define SSQ2_OFF   2604   // 1792
#define ZERO_N     4396   // floats zeroed every launch
#define BIAS1_OFF  4396   // 1792
#define SCALE2_OFF 6188   // 1792
#define SHIFT2_OFF 7980   // 1792
#define BF_BASE_F  9984   // bf16 region starts here (byte 39936, 16B aligned)
#define W2B_OFF_S  57344  // short offset of W2 bf16 within bf16 region

__device__ __forceinline__ float gelu_f(float x) {
    return 0.5f * x * (1.0f + erff(x * 0.70710678118654752f));
}
__device__ __forceinline__ short f2bf(float x) {
    __hip_bfloat16 h = __float2bfloat16(x);
    return __builtin_bit_cast(short, h);
}

// ---------------- zero the atomic-accumulated stats region ----------------
__global__ void k_zero(float* __restrict__ ws) {
    int i = blockIdx.x * 256 + threadIdx.x;
    if (i < ZERO_N) ws[i] = 0.0f;
}

// ---------------- X column sums and Gram matrix (for analytic BN1) --------
__global__ __launch_bounds__(256) void k_xstats(const float* __restrict__ X,
                                                float* __restrict__ ws) {
    __shared__ float sx[128 * 28];
    const int tid = threadIdx.x;
    float acc[4] = {0.f, 0.f, 0.f, 0.f};
    const int rowbase = blockIdx.x * 512;
    for (int c = 0; c < 4; ++c) {
        const f4* src = (const f4*)(X + (size_t)(rowbase + c * 128) * 28);
        f4* dst = (f4*)sx;
        for (int i = tid; i < 128 * 28 / 4; i += 256) dst[i] = src[i];
        __syncthreads();
#pragma unroll
        for (int s = 0; s < 4; ++s) {
            int slot = tid + s * 256;
            if (slot < 812) {
                float a = acc[s];
                if (slot < 28) {
                    for (int r = 0; r < 128; ++r) a += sx[r * 28 + slot];
                } else {
                    int p = slot - 28;
                    int d = p / 28, e = p % 28;
                    for (int r = 0; r < 128; ++r) a += sx[r * 28 + d] * sx[r * 28 + e];
                }
                acc[s] = a;
            }
        }
        __syncthreads();
    }
#pragma unroll
    for (int s = 0; s < 4; ++s) {
        int slot = tid + s * 256;
        if (slot < 812) atomicAdd(&ws[slot], acc[s]);
    }
}

// ------- fold: W = sigmoid mask, analytic BN1 -> folded bf16 weights ------
__global__ __launch_bounds__(64) void k_fold1(const float* __restrict__ Wlog,
                                              const float* __restrict__ W1,
                                              const float* __restrict__ b1,
                                              const float* __restrict__ g1,
                                              const float* __restrict__ be1,
                                              const float* __restrict__ W2,
                                              float* __restrict__ ws,
                                              float* __restrict__ out_w) {
    __shared__ float wrow[28], mu[28], C[784];
    const int n = blockIdx.x, t = threadIdx.x;
    if (t < 28) {
        float w = 1.0f / (1.0f + expf(-Wlog[n * 28 + t]));
        if (t == n) w = 0.0f;
        wrow[t] = w;
        out_w[n * 28 + t] = w;      // second output: the adjacency W
        mu[t] = ws[SX_OFF + t] * (1.0f / 32768.0f);
    }
    __syncthreads();
    for (int i = t; i < 784; i += 64) {
        int d = i / 28, e = i % 28;
        C[i] = ws[SXX_OFF + i] * (1.0f / 32768.0f) - mu[d] * mu[e];
    }
    __syncthreads();
    // this thread owns hidden unit h = t of mechanism n
    float w1e[28];
#pragma unroll
    for (int d = 0; d < 28; ++d) w1e[d] = W1[(n * 64 + t) * 28 + d] * wrow[d];
    float mean = b1[n * 64 + t];
#pragma unroll
    for (int d = 0; d < 28; ++d) mean += w1e[d] * mu[d];
    float var = 0.0f;
    for (int d = 0; d < 28; ++d) {
        float tmp = 0.0f;
        for (int e = 0; e < 28; ++e) tmp += C[d * 28 + e] * w1e[e];
        var += tmp * w1e[d];
    }
    var = fmaxf(var, 0.0f);
    float scale = g1[n * 64 + t] * rsqrtf(var + BN_EPS);
    ws[BIAS1_OFF + n * 64 + t] = be1[n * 64 + t] + (b1[n * 64 + t] - mean) * scale;
    short* bfbase = (short*)(ws + BF_BASE_F);
    short* w1f = bfbase + (size_t)(n * 64 + t) * 32;
#pragma unroll
    for (int d = 0; d < 32; ++d) w1f[d] = f2bf(d < 28 ? w1e[d] * scale : 0.0f);
    short* w2b = bfbase + W2B_OFF_S + (size_t)(n * 64 + t) * 64;
#pragma unroll
    for (int h = 0; h < 64; ++h) w2b[h] = f2bf(W2[((size_t)n * 64 + t) * 64 + h]);
}

// ---------------- finalize BN2 affine from accumulated sums ----------------
__global__ void k_fold2(const float* __restrict__ g2, const float* __restrict__ be2,
                        float* __restrict__ ws) {
    int i = blockIdx.x * 256 + threadIdx.x;
    if (i < 1792) {
        float mean = ws[SUM2_OFF + i] * (1.0f / 32768.0f);
        float var  = ws[SSQ2_OFF + i] * (1.0f / 32768.0f) - mean * mean;
        float sc = g2[i] * rsqrtf(fmaxf(var, 0.0f) + BN_EPS);
        ws[SCALE2_OFF + i] = sc;
        ws[SHIFT2_OFF + i] = be2[i] - mean * sc;
    }
}

// ---------------- fused GEMM1+gelu+GEMM2 (+stats | +BN2+gelu+GEMM3) -------
template <bool PASS1>
__global__ __launch_bounds__(256) void k_main(const float* __restrict__ X,
                                              const float* __restrict__ b2,
                                              const float* __restrict__ W3,
                                              const float* __restrict__ b3,
                                              float* __restrict__ ws,
                                              float* __restrict__ out) {
    __shared__ __align__(16) short sW1[64 * 40];        // [h][d pad 32->40]
    __shared__ __align__(16) short sW2[64 * 72];        // [g][h pad 64->72]
    __shared__ __align__(16) short sA1[4 * 16 * 72];    // per-wave [m][h pad 72]
    __shared__ float sSum[64], sSsq[64];

    const int bid = blockIdx.x;
    const int n = bid >> 9;           // 512 m-blocks per mechanism
    const int mblk = bid & 511;
    const int tid = threadIdx.x;
    const int wave = tid >> 6;
    const int lane = tid & 63;
    const int m = lane & 15;
    const int q = lane >> 4;

    const short* bfbase = (const short*)(ws + BF_BASE_F);
    const short* w1g = bfbase + (size_t)n * 64 * 32;
    const short* w2g = bfbase + W2B_OFF_S + (size_t)n * 64 * 64;
    {   // stage folded weights into padded LDS
        int r = tid >> 2, c = tid & 3;
        *(s8*)&sW1[r * 40 + c * 8] = *(const s8*)&w1g[r * 32 + c * 8];
#pragma unroll
        for (int k = 0; k < 2; ++k) {
            int i2 = tid + k * 256;
            int r2 = i2 >> 3, c2 = i2 & 7;
            *(s8*)&sW2[r2 * 72 + c2 * 8] = *(const s8*)&w2g[r2 * 64 + c2 * 8];
        }
        if (PASS1 && tid < 64) { sSum[tid] = 0.0f; sSsq[tid] = 0.0f; }
    }
    __syncthreads();

    const int row0 = mblk * 64 + wave * 16;

    // B-frag of GEMM1: lane holds X[row0+m][8q..8q+7] (d=28..31 zero-padded)
    s8 xf;
    {
        const float* xr = X + (size_t)(row0 + m) * 28 + q * 8;
        f4 fa = *(const f4*)xr;
        f4 fb;
        if (q < 3) fb = *(const f4*)(xr + 4);
        else       fb = (f4){0.f, 0.f, 0.f, 0.f};
        xf[0] = f2bf(fa[0]); xf[1] = f2bf(fa[1]); xf[2] = f2bf(fa[2]); xf[3] = f2bf(fa[3]);
        xf[4] = f2bf(fb[0]); xf[5] = f2bf(fb[1]); xf[6] = f2bf(fb[2]); xf[7] = f2bf(fb[3]);
    }

    // GEMM1: D[h][m] = sum_d W1fold[h][d] * X^T[d][m]
    f4 acc1[4];
#pragma unroll
    for (int t = 0; t < 4; ++t) {
        s8 wf = *(const s8*)&sW1[(16 * t + m) * 40 + q * 8];
        acc1[t] = __builtin_amdgcn_mfma_f32_16x16x32_bf16(wf, xf, (f4){0.f, 0.f, 0.f, 0.f}, 0, 0, 0);
    }

    // epilogue 1: +bias, gelu, pack bf16, store a1[m][h] (reg dim = 4 consecutive h)
    const float* bias1 = ws + BIAS1_OFF + n * 64;
    short* myA1 = &sA1[wave * 16 * 72];
#pragma unroll
    for (int t = 0; t < 4; ++t) {
        f4 bv = *(const f4*)&bias1[16 * t + 4 * q];
        s4 p;
#pragma unroll
        for (int r = 0; r < 4; ++r) p[r] = f2bf(gelu_f(acc1[t][r] + bv[r]));
        *(s4*)&myA1[m * 72 + 16 * t + 4 * q] = p;
    }
    __syncthreads();

    // GEMM2: D2[g][m] = sum_h W2[g][h] * a1^T[h][m]
    s8 af0 = *(const s8*)&myA1[m * 72 + 8 * q];
    s8 af1 = *(const s8*)&myA1[m * 72 + 32 + 8 * q];
    f4 acc2[4];
#pragma unroll
    for (int u = 0; u < 4; ++u) {
        s8 w0 = *(const s8*)&sW2[(16 * u + m) * 72 + 8 * q];
        s8 w1 = *(const s8*)&sW2[(16 * u + m) * 72 + 32 + 8 * q];
        f4 a = (f4){0.f, 0.f, 0.f, 0.f};
        a = __builtin_amdgcn_mfma_f32_16x16x32_bf16(w0, af0, a, 0, 0, 0);
        a = __builtin_amdgcn_mfma_f32_16x16x32_bf16(w1, af1, a, 0, 0, 0);
        acc2[u] = a;
    }

    const float* b2n = b2 + n * 64;
    if (PASS1) {
        // accumulate batch sum / sumsq of h2 per (n,g)
#pragma unroll
        for (int u = 0; u < 4; ++u) {
            f4 bv = *(const f4*)&b2n[16 * u + 4 * q];
#pragma unroll
            for (int r = 0; r < 4; ++r) {
                float v = acc2[u][r] + bv[r];
                float s = v, s2 = v * v;
                s += __shfl_xor(s, 1);  s2 += __shfl_xor(s2, 1);
                s += __shfl_xor(s, 2);  s2 += __shfl_xor(s2, 2);
                s += __shfl_xor(s, 4);  s2 += __shfl_xor(s2, 4);
                s += __shfl_xor(s, 8);  s2 += __shfl_xor(s2, 8);
                if (m == 0) {
                    atomicAdd(&sSum[16 * u + 4 * q + r], s);
                    atomicAdd(&sSsq[16 * u + 4 * q + r], s2);
                }
            }
        }
        __syncthreads();
        if (tid < 64) {
            atomicAdd(&ws[SUM2_OFF + n * 64 + tid], sSum[tid]);
            atomicAdd(&ws[SSQ2_OFF + n * 64 + tid], sSsq[tid]);
        }
    } else {
        // BN2 affine + gelu + dot with W3 (all fp32 in registers)
        const float* sc = ws + SCALE2_OFF + n * 64;
        const float* sh = ws + SHIFT2_OFF + n * 64;
        const float* w3 = W3 + n * 64;
        float p = 0.0f;
#pragma unroll
        for (int u = 0; u < 4; ++u) {
            f4 bv  = *(const f4*)&b2n[16 * u + 4 * q];
            f4 scv = *(const f4*)&sc[16 * u + 4 * q];
            f4 shv = *(const f4*)&sh[16 * u + 4 * q];
            f4 w3v = *(const f4*)&w3[16 * u + 4 * q];
#pragma unroll
            for (int r = 0; r < 4; ++r) {
                float v = acc2[u][r] + bv[r];
                float a2 = gelu_f(v * scv[r] + shv[r]);
                p += a2 * w3v[r];
            }
        }
        p += __shfl_xor(p, 16);
        p += __shfl_xor(p, 32);
        if (q == 0) out[(size_t)(row0 + m) * 28 + n] = p + b3[n];
    }
}

extern "C" void kernel_launch(void* const* d_in, const int* in_sizes, int n_in,
                              void* d_out, int out_size, void* d_ws, size_t ws_size,
                              hipStream_t stream) {
    const float* X   = (const float*)d_in[0];
    const float* Wl  = (const float*)d_in[1];
    const float* W1  = (const float*)d_in[2];
    const float* b1  = (const float*)d_in[3];
    const float* g1  = (const float*)d_in[4];
    const float* be1 = (const float*)d_in[5];
    const float* W2  = (const float*)d_in[6];
    const float* b2  = (const float*)d_in[7];
    const float* g2  = (const float*)d_in[8];
    const float* be2 = (const float*)d_in[9];
    const float* W3  = (const float*)d_in[10];
    const float* b3  = (const float*)d_in[11];
    float* out = (float*)d_out;
    float* ws  = (float*)d_ws;

    k_zero<<<dim3(18), dim3(256), 0, stream>>>(ws);
    k_xstats<<<dim3(64), dim3(256), 0, stream>>>(X, ws);
    k_fold1<<<dim3(28), dim3(64), 0, stream>>>(Wl, W1, b1, g1, be1, W2, ws, out + 917504);
    k_main<true><<<dim3(28 * 512), dim3(256), 0, stream>>>(X, b2, W3, b3, ws, out);
    k_fold2<<<dim3(7), dim3(256), 0, stream>>>(g2, be2, ws);
    k_main<false><<<dim3(28 * 512), dim3(256), 0, stream>>>(X, b2, W3, b3, ws, out);
}

// Round 2
// 325.898 us; speedup vs baseline: 1.2399x; 1.2399x over previous
//
#include <hip/hip_runtime.h>
#include <hip/hip_bf16.h>
#include <math.h>

typedef float  f4 __attribute__((ext_vector_type(4)));
typedef short  s8 __attribute__((ext_vector_type(8)));
typedef short  s4 __attribute__((ext_vector_type(4)));

#define NV 28
#define HID 64
#define NB 32768
#define BN_EPS 1e-5f

// ---- workspace layout (float indices unless noted) ----
#define SUM2_OFF   0        // 1792
#define SSQ2_OFF   1792     // 1792
#define BIAS1_OFF  3584     // 1792
#define PART_OFF   5376     // 32 * 812 = 25984
#define BF_BASE_F  31360    // bf16 region (byte 125440, 16B aligned)
#define W2B_OFF_S  57344    // short offset of W2 bf16 within bf16 region
#define H2_BYTE_OFF 469504ull         // byte offset of bf16 h2 buffer
#define H2_BYTES    117440512ull      // 28*32768*64*2

// fast gelu: x * sigmoid(2*0.79788456*(x+0.044715x^3)) via hw exp2/rcp
// max abs err vs exact erf-gelu ~5e-4
__device__ __forceinline__ float gelu_f(float x) {
    float x2 = x * x;
    float z  = x * __builtin_fmaf(x2, -0.10294324f, -2.3022082f);
    float t  = __builtin_amdgcn_exp2f(z);
    return x * __builtin_amdgcn_rcpf(1.0f + t);
}
__device__ __forceinline__ short f2bf(float x) {
    __hip_bfloat16 h = __float2bfloat16(x);
    return __builtin_bit_cast(short, h);
}
__device__ __forceinline__ float bf2f(short s) {
    return __builtin_bit_cast(float, ((int)(unsigned short)s) << 16);
}
// sum over the 16 lanes of a DPP row (our m-dimension): all lanes get the total
__device__ __forceinline__ float row16_sum(float v) {
    int x;
    x = __builtin_amdgcn_update_dpp(0, __builtin_bit_cast(int, v), 0xB1, 0xF, 0xF, true);  // quad_perm xor1
    v += __builtin_bit_cast(float, x);
    x = __builtin_amdgcn_update_dpp(0, __builtin_bit_cast(int, v), 0x4E, 0xF, 0xF, true);  // quad_perm xor2
    v += __builtin_bit_cast(float, x);
    x = __builtin_amdgcn_update_dpp(0, __builtin_bit_cast(int, v), 0x124, 0xF, 0xF, true); // row_ror:4
    v += __builtin_bit_cast(float, x);
    x = __builtin_amdgcn_update_dpp(0, __builtin_bit_cast(int, v), 0x128, 0xF, 0xF, true); // row_ror:8
    v += __builtin_bit_cast(float, x);
    return v;
}

// ---------------- X column sums and Gram matrix partials (no atomics) -----
__global__ __launch_bounds__(256) void k_xstats(const float* __restrict__ X,
                                                float* __restrict__ ws) {
    __shared__ float sx[128 * 28];
    const int tid = threadIdx.x;
    float acc[4] = {0.f, 0.f, 0.f, 0.f};
    const int rowbase = blockIdx.x * 1024;
    for (int c = 0; c < 8; ++c) {
        const f4* src = (const f4*)(X + (size_t)(rowbase + c * 128) * 28);
        f4* dst = (f4*)sx;
        for (int i = tid; i < 128 * 28 / 4; i += 256) dst[i] = src[i];
        __syncthreads();
#pragma unroll
        for (int s = 0; s < 4; ++s) {
            int slot = tid + s * 256;
            if (slot < 812) {
                float a = acc[s];
                if (slot < 28) {
                    for (int r = 0; r < 128; ++r) a += sx[r * 28 + slot];
                } else {
                    int p = slot - 28;
                    int d = p / 28, e = p % 28;
                    for (int r = 0; r < 128; ++r) a += sx[r * 28 + d] * sx[r * 28 + e];
                }
                acc[s] = a;
            }
        }
        __syncthreads();
    }
#pragma unroll
    for (int s = 0; s < 4; ++s) {
        int slot = tid + s * 256;
        if (slot < 812) ws[PART_OFF + blockIdx.x * 812 + slot] = acc[s];
    }
}

// ------- fold: sigmoid mask, analytic BN1 -> folded bf16 weights ---------
// also reduces xstats partials and zeroes the pass-1 stat accumulators
__global__ __launch_bounds__(64) void k_fold1(const float* __restrict__ Wlog,
                                              const float* __restrict__ W1,
                                              const float* __restrict__ b1,
                                              const float* __restrict__ g1,
                                              const float* __restrict__ be1,
                                              const float* __restrict__ W2,
                                              float* __restrict__ ws,
                                              float* __restrict__ out_w) {
    __shared__ float sstat[812];
    __shared__ float wrow[28], mu[28], C[784];
    const int n = blockIdx.x, t = threadIdx.x;
    for (int i = t; i < 812; i += 64) {
        float a = 0.f;
#pragma unroll 8
        for (int p = 0; p < 32; ++p) a += ws[PART_OFF + p * 812 + i];
        sstat[i] = a;
    }
    ws[SUM2_OFF + n * 64 + t] = 0.0f;   // zero stat accumulators for pass 1
    ws[SSQ2_OFF + n * 64 + t] = 0.0f;
    __syncthreads();
    if (t < 28) {
        float w = 1.0f / (1.0f + expf(-Wlog[n * 28 + t]));
        if (t == n) w = 0.0f;
        wrow[t] = w;
        out_w[n * 28 + t] = w;          // second output: adjacency W
        mu[t] = sstat[t] * (1.0f / 32768.0f);
    }
    __syncthreads();
    for (int i = t; i < 784; i += 64) {
        int d = i / 28, e = i % 28;
        C[i] = sstat[28 + i] * (1.0f / 32768.0f) - mu[d] * mu[e];
    }
    __syncthreads();
    float w1e[28];
#pragma unroll
    for (int d = 0; d < 28; ++d) w1e[d] = W1[(n * 64 + t) * 28 + d] * wrow[d];
    float mean = b1[n * 64 + t];
#pragma unroll
    for (int d = 0; d < 28; ++d) mean += w1e[d] * mu[d];
    float var = 0.0f;
    for (int d = 0; d < 28; ++d) {
        float tmp = 0.0f;
        for (int e = 0; e < 28; ++e) tmp += C[d * 28 + e] * w1e[e];
        var += tmp * w1e[d];
    }
    var = fmaxf(var, 0.0f);
    float scale = g1[n * 64 + t] * rsqrtf(var + BN_EPS);
    ws[BIAS1_OFF + n * 64 + t] = be1[n * 64 + t] + (b1[n * 64 + t] - mean) * scale;
    short* bfbase = (short*)(ws + BF_BASE_F);
    short* w1f = bfbase + (size_t)(n * 64 + t) * 32;
#pragma unroll
    for (int d = 0; d < 32; ++d) w1f[d] = f2bf(d < 28 ? w1e[d] * scale : 0.0f);
    short* w2b = bfbase + W2B_OFF_S + (size_t)(n * 64 + t) * 64;
#pragma unroll
    for (int h = 0; h < 64; ++h) w2b[h] = f2bf(W2[((size_t)n * 64 + t) * 64 + h]);
}

// ---------------- pass 1: GEMM1+gelu+GEMM2, h2 stats (+optional h2 store) -
template <bool STORE>
__global__ __launch_bounds__(256) void k_pass1(const float* __restrict__ X,
                                               const float* __restrict__ b2,
                                               float* __restrict__ ws,
                                               short* __restrict__ h2buf) {
    __shared__ __align__(16) short sW1[64 * 40];
    __shared__ __align__(16) short sW2[64 * 72];
    __shared__ __align__(16) short sA1[4 * 16 * 72];
    __shared__ float sSum[64], sSsq[64];

    const int bid = blockIdx.x;
    const int n = bid >> 9;
    const int mblk = bid & 511;
    const int tid = threadIdx.x;
    const int wave = tid >> 6;
    const int lane = tid & 63;
    const int m = lane & 15;
    const int q = lane >> 4;

    const short* bfbase = (const short*)(ws + BF_BASE_F);
    const short* w1g = bfbase + (size_t)n * 64 * 32;
    const short* w2g = bfbase + W2B_OFF_S + (size_t)n * 64 * 64;
    {
        int r = tid >> 2, c = tid & 3;
        *(s8*)&sW1[r * 40 + c * 8] = *(const s8*)&w1g[r * 32 + c * 8];
#pragma unroll
        for (int k = 0; k < 2; ++k) {
            int i2 = tid + k * 256;
            int r2 = i2 >> 3, c2 = i2 & 7;
            *(s8*)&sW2[r2 * 72 + c2 * 8] = *(const s8*)&w2g[r2 * 64 + c2 * 8];
        }
        if (tid < 64) { sSum[tid] = 0.0f; sSsq[tid] = 0.0f; }
    }
    __syncthreads();

    const int row0 = mblk * 64 + wave * 16;

    s8 xf;
    {
        const float* xr = X + (size_t)(row0 + m) * 28 + q * 8;
        f4 fa = *(const f4*)xr;
        f4 fb;
        if (q < 3) fb = *(const f4*)(xr + 4);
        else       fb = (f4){0.f, 0.f, 0.f, 0.f};
        xf[0] = f2bf(fa[0]); xf[1] = f2bf(fa[1]); xf[2] = f2bf(fa[2]); xf[3] = f2bf(fa[3]);
        xf[4] = f2bf(fb[0]); xf[5] = f2bf(fb[1]); xf[6] = f2bf(fb[2]); xf[7] = f2bf(fb[3]);
    }

    f4 acc1[4];
#pragma unroll
    for (int t = 0; t < 4; ++t) {
        s8 wf = *(const s8*)&sW1[(16 * t + m) * 40 + q * 8];
        acc1[t] = __builtin_amdgcn_mfma_f32_16x16x32_bf16(wf, xf, (f4){0.f, 0.f, 0.f, 0.f}, 0, 0, 0);
    }

    const float* bias1 = ws + BIAS1_OFF + n * 64;
    short* myA1 = &sA1[wave * 16 * 72];
#pragma unroll
    for (int t = 0; t < 4; ++t) {
        f4 bv = *(const f4*)&bias1[16 * t + 4 * q];
        s4 p;
#pragma unroll
        for (int r = 0; r < 4; ++r) p[r] = f2bf(gelu_f(acc1[t][r] + bv[r]));
        *(s4*)&myA1[m * 72 + 16 * t + 4 * q] = p;
    }
    __syncthreads();

    s8 af0 = *(const s8*)&myA1[m * 72 + 8 * q];
    s8 af1 = *(const s8*)&myA1[m * 72 + 32 + 8 * q];
    f4 acc2[4];
#pragma unroll
    for (int u = 0; u < 4; ++u) {
        s8 w0 = *(const s8*)&sW2[(16 * u + m) * 72 + 8 * q];
        s8 w1 = *(const s8*)&sW2[(16 * u + m) * 72 + 32 + 8 * q];
        f4 a = (f4){0.f, 0.f, 0.f, 0.f};
        a = __builtin_amdgcn_mfma_f32_16x16x32_bf16(w0, af0, a, 0, 0, 0);
        a = __builtin_amdgcn_mfma_f32_16x16x32_bf16(w1, af1, a, 0, 0, 0);
        acc2[u] = a;
    }

    const float* b2n = b2 + n * 64;
    short* hp = STORE ? (h2buf + ((size_t)n * NB + row0 + m) * 64) : nullptr;
#pragma unroll
    for (int u = 0; u < 4; ++u) {
        f4 bv = *(const f4*)&b2n[16 * u + 4 * q];
        s4 hpak;
#pragma unroll
        for (int r = 0; r < 4; ++r) {
            float v = acc2[u][r] + bv[r];
            if (STORE) hpak[r] = f2bf(v);
            float s  = row16_sum(v);
            float s2 = row16_sum(v * v);
            if (m == 0) {
                atomicAdd(&sSum[16 * u + 4 * q + r], s);
                atomicAdd(&sSsq[16 * u + 4 * q + r], s2);
            }
        }
        if (STORE) *(s4*)&hp[16 * u + 4 * q] = hpak;
    }
    __syncthreads();
    if (tid < 64) {
        atomicAdd(&ws[SUM2_OFF + n * 64 + tid], sSum[tid]);
        atomicAdd(&ws[SSQ2_OFF + n * 64 + tid], sSsq[tid]);
    }
}

// ---------------- pass 2 (stored h2): BN2 + gelu + GEMM3 ------------------
__global__ __launch_bounds__(256) void k_pass2s(const float* __restrict__ g2,
                                                const float* __restrict__ be2,
                                                const float* __restrict__ W3,
                                                const float* __restrict__ b3,
                                                const float* __restrict__ ws,
                                                const short* __restrict__ h2buf,
                                                float* __restrict__ out) {
    __shared__ float sSc[64], sSh[64], sW3v[64];
    const int bid = blockIdx.x;
    const int n = bid >> 9;
    const int mblk = bid & 511;
    const int tid = threadIdx.x;
    const int wave = tid >> 6;
    const int lane = tid & 63;
    const int m = lane & 15;
    const int q = lane >> 4;

    if (tid < 64) {
        float mean = ws[SUM2_OFF + n * 64 + tid] * (1.0f / 32768.0f);
        float var  = ws[SSQ2_OFF + n * 64 + tid] * (1.0f / 32768.0f) - mean * mean;
        float sc = g2[n * 64 + tid] * rsqrtf(fmaxf(var, 0.0f) + BN_EPS);
        sSc[tid] = sc;
        sSh[tid] = be2[n * 64 + tid] - mean * sc;
        sW3v[tid] = W3[n * 64 + tid];
    }
    __syncthreads();

    const int row0 = mblk * 64 + wave * 16;
    const short* hp = h2buf + ((size_t)n * NB + row0 + m) * 64;
    float p = 0.0f;
#pragma unroll
    for (int u = 0; u < 4; ++u) {
        s4 pv = *(const s4*)&hp[16 * u + 4 * q];
        f4 scv = *(const f4*)&sSc[16 * u + 4 * q];
        f4 shv = *(const f4*)&sSh[16 * u + 4 * q];
        f4 w3v = *(const f4*)&sW3v[16 * u + 4 * q];
#pragma unroll
        for (int r = 0; r < 4; ++r) {
            float v = bf2f(pv[r]);
            p += gelu_f(__builtin_fmaf(v, scv[r], shv[r])) * w3v[r];
        }
    }
    p += __shfl_xor(p, 16);
    p += __shfl_xor(p, 32);
    if (q == 0) out[(size_t)(row0 + m) * 28 + n] = p + b3[n];
}

// ------- pass 2 fallback (no h2 storage): full recompute + BN2 + GEMM3 ----
__global__ __launch_bounds__(256) void k_pass2r(const float* __restrict__ X,
                                                const float* __restrict__ b2,
                                                const float* __restrict__ g2,
                                                const float* __restrict__ be2,
                                                const float* __restrict__ W3,
                                                const float* __restrict__ b3,
                                                float* __restrict__ ws,
                                                float* __restrict__ out) {
    __shared__ __align__(16) short sW1[64 * 40];
    __shared__ __align__(16) short sW2[64 * 72];
    __shared__ __align__(16) short sA1[4 * 16 * 72];
    __shared__ float sSc[64], sSh[64], sW3v[64];

    const int bid = blockIdx.x;
    const int n = bid >> 9;
    const int mblk = bid & 511;
    const int tid = threadIdx.x;
    const int wave = tid >> 6;
    const int lane = tid & 63;
    const int m = lane & 15;
    const int q = lane >> 4;

    const short* bfbase = (const short*)(ws + BF_BASE_F);
    const short* w1g = bfbase + (size_t)n * 64 * 32;
    const short* w2g = bfbase + W2B_OFF_S + (size_t)n * 64 * 64;
    {
        int r = tid >> 2, c = tid & 3;
        *(s8*)&sW1[r * 40 + c * 8] = *(const s8*)&w1g[r * 32 + c * 8];
#pragma unroll
        for (int k = 0; k < 2; ++k) {
            int i2 = tid + k * 256;
            int r2 = i2 >> 3, c2 = i2 & 7;
            *(s8*)&sW2[r2 * 72 + c2 * 8] = *(const s8*)&w2g[r2 * 64 + c2 * 8];
        }
        if (tid < 64) {
            float mean = ws[SUM2_OFF + n * 64 + tid] * (1.0f / 32768.0f);
            float var  = ws[SSQ2_OFF + n * 64 + tid] * (1.0f / 32768.0f) - mean * mean;
            float sc = g2[n * 64 + tid] * rsqrtf(fmaxf(var, 0.0f) + BN_EPS);
            sSc[tid] = sc;
            sSh[tid] = be2[n * 64 + tid] - mean * sc;
            sW3v[tid] = W3[n * 64 + tid];
        }
    }
    __syncthreads();

    const int row0 = mblk * 64 + wave * 16;

    s8 xf;
    {
        const float* xr = X + (size_t)(row0 + m) * 28 + q * 8;
        f4 fa = *(const f4*)xr;
        f4 fb;
        if (q < 3) fb = *(const f4*)(xr + 4);
        else       fb = (f4){0.f, 0.f, 0.f, 0.f};
        xf[0] = f2bf(fa[0]); xf[1] = f2bf(fa[1]); xf[2] = f2bf(fa[2]); xf[3] = f2bf(fa[3]);
        xf[4] = f2bf(fb[0]); xf[5] = f2bf(fb[1]); xf[6] = f2bf(fb[2]); xf[7] = f2bf(fb[3]);
    }

    f4 acc1[4];
#pragma unroll
    for (int t = 0; t < 4; ++t) {
        s8 wf = *(const s8*)&sW1[(16 * t + m) * 40 + q * 8];
        acc1[t] = __builtin_amdgcn_mfma_f32_16x16x32_bf16(wf, xf, (f4){0.f, 0.f, 0.f, 0.f}, 0, 0, 0);
    }

    const float* bias1 = ws + BIAS1_OFF + n * 64;
    short* myA1 = &sA1[wave * 16 * 72];
#pragma unroll
    for (int t = 0; t < 4; ++t) {
        f4 bv = *(const f4*)&bias1[16 * t + 4 * q];
        s4 p;
#pragma unroll
        for (int r = 0; r < 4; ++r) p[r] = f2bf(gelu_f(acc1[t][r] + bv[r]));
        *(s4*)&myA1[m * 72 + 16 * t + 4 * q] = p;
    }
    __syncthreads();

    s8 af0 = *(const s8*)&myA1[m * 72 + 8 * q];
    s8 af1 = *(const s8*)&myA1[m * 72 + 32 + 8 * q];
    f4 acc2[4];
#pragma unroll
    for (int u = 0; u < 4; ++u) {
        s8 w0 = *(const s8*)&sW2[(16 * u + m) * 72 + 8 * q];
        s8 w1 = *(const s8*)&sW2[(16 * u + m) * 72 + 32 + 8 * q];
        f4 a = (f4){0.f, 0.f, 0.f, 0.f};
        a = __builtin_amdgcn_mfma_f32_16x16x32_bf16(w0, af0, a, 0, 0, 0);
        a = __builtin_amdgcn_mfma_f32_16x16x32_bf16(w1, af1, a, 0, 0, 0);
        acc2[u] = a;
    }

    const float* b2n = b2 + n * 64;
    float p = 0.0f;
#pragma unroll
    for (int u = 0; u < 4; ++u) {
        f4 bv  = *(const f4*)&b2n[16 * u + 4 * q];
        f4 scv = *(const f4*)&sSc[16 * u + 4 * q];
        f4 shv = *(const f4*)&sSh[16 * u + 4 * q];
        f4 w3v = *(const f4*)&sW3v[16 * u + 4 * q];
#pragma unroll
        for (int r = 0; r < 4; ++r) {
            float v = acc2[u][r] + bv[r];
            p += gelu_f(__builtin_fmaf(v, scv[r], shv[r])) * w3v[r];
        }
    }
    p += __shfl_xor(p, 16);
    p += __shfl_xor(p, 32);
    if (q == 0) out[(size_t)(row0 + m) * 28 + n] = p + b3[n];
}

extern "C" void kernel_launch(void* const* d_in, const int* in_sizes, int n_in,
                              void* d_out, int out_size, void* d_ws, size_t ws_size,
                              hipStream_t stream) {
    const float* X   = (const float*)d_in[0];
    const float* Wl  = (const float*)d_in[1];
    const float* W1  = (const float*)d_in[2];
    const float* b1  = (const float*)d_in[3];
    const float* g1  = (const float*)d_in[4];
    const float* be1 = (const float*)d_in[5];
    const float* W2  = (const float*)d_in[6];
    const float* b2  = (const float*)d_in[7];
    const float* g2  = (const float*)d_in[8];
    const float* be2 = (const float*)d_in[9];
    const float* W3  = (const float*)d_in[10];
    const float* b3  = (const float*)d_in[11];
    float* out = (float*)d_out;
    float* ws  = (float*)d_ws;
    short* h2buf = (short*)((char*)d_ws + H2_BYTE_OFF);
    const bool store_h2 = ws_size >= H2_BYTE_OFF + H2_BYTES;

    k_xstats<<<dim3(32), dim3(256), 0, stream>>>(X, ws);
    k_fold1<<<dim3(28), dim3(64), 0, stream>>>(Wl, W1, b1, g1, be1, W2, ws, out + 917504);
    if (store_h2) {
        k_pass1<true><<<dim3(28 * 512), dim3(256), 0, stream>>>(X, b2, ws, h2buf);
        k_pass2s<<<dim3(28 * 512), dim3(256), 0, stream>>>(g2, be2, W3, b3, ws, h2buf, out);
    } else {
        k_pass1<false><<<dim3(28 * 512), dim3(256), 0, stream>>>(X, b2, ws, nullptr);
        k_pass2r<<<dim3(28 * 512), dim3(256), 0, stream>>>(X, b2, g2, be2, W3, b3, ws, out);
    }
}